// Round 14
// baseline (2887.425 us; speedup 1.0000x reference)
//
#include <hip/hip_runtime.h>

#define HP   768      // padded H (=W)
#define NV   385      // HP/2 + 1
#define HIN  512
#define WIN  512
#define K    8        // truncation radius of spatial inverse kernel
#define A    17       // 2K+1
#define PADO 136      // PAD + K = 128 + 8
#define TW   64       // output tile width
#define TH   64       // output tile height
#define LH   80       // TH + 2K staged rows
#define LWL  80       // TW + 2K (logical tile width)
#define LWS  84       // LDS stride between compute-rows (84 words)
#define SUBROWS 20    // compute-rows per 4-way parity sub-array (80/4)
#define SUBSIZE (SUBROWS * LWS)   // 1680 floats

#define OB   120      // active-region origin: nonzero out rows/cols = [120, 648)
#define OE   648      // active-region end (exclusive)
#define NT9  9        // 9x9 tiles cover [120, 696) >= [120, 648)
#define ACT0_Q 30     // 120/4  (float4 index of active col start)
#define ACT1_Q 174    // 696/4  (float4 index of active col end)
#define OTS  65       // out-transpose LDS row stride (64+1)

#define TWO_PI_OVER_HP 0.008181230868723419f  // 2*pi/768

typedef float f4v __attribute__((ext_vector_type(4)));

__device__ inline float2 cmul(float2 a, float2 b) {
    return make_float2(a.x*b.x - a.y*b.y, a.x*b.y + a.y*b.x);
}

// F(u,v) = sum_{i<3,j<3} w[i,j] * exp(-2*pi*i*(u*i + v*j)/768), via LDS table
__device__ inline float2 evalF_t(int u, int v, const float* w9,
                                 const float2* __restrict__ tbl) {
    float fr = 0.f, fi = 0.f;
#pragma unroll
    for (int i = 0; i < 3; ++i) {
#pragma unroll
        for (int j = 0; j < 3; ++j) {
            int idx = u * i + v * j;          // <= 2302
            if (idx >= 2 * HP) idx -= 2 * HP;
            if (idx >= HP)     idx -= HP;
            float2 e = tbl[idx];
            float wv = w9[i * 3 + j];
            fr += wv * e.x;
            fi -= wv * e.y;
        }
    }
    return make_float2(fr, fi);
}

// One block per rfft column v. Builds gmf[.,v] in LDS, then
// P[a,v] = sum_u gmf[u,v] * exp(+2*pi*i*u*(a-K)/768)  for all 17 taps,
// parallelized 16 threads per tap.
__global__ __launch_bounds__(320) void filt_P_kernel(
        const float* __restrict__ w, float2* __restrict__ P) {
    __shared__ float2 tbl[HP];
    __shared__ float2 lg[HP];
    __shared__ float2 red[20][16];
    int v = blockIdx.x;
    int tid = threadIdx.x;

    float w9[9];
#pragma unroll
    for (int i = 0; i < 9; ++i) w9[i] = w[i];

    for (int m = tid; m < HP; m += 320) {
        float s, c;
        sincosf((float)m * TWO_PI_OVER_HP, &s, &c);
        tbl[m] = make_float2(c, s);
    }
    __syncthreads();

    int sv = (v == 0) ? 0 : (NV - v);   // reference's reverse+roll index
    for (int u = tid; u < HP; u += 320) {
        int su = (HP - u) % HP;
        float2 F1 = evalF_t(u,  v,  w9, tbl);
        float2 F2 = evalF_t(su, v,  w9, tbl);
        float2 F3 = evalF_t(u,  sv, w9, tbl);
        float2 F4 = evalF_t(su, sv, w9, tbl);
        float2 pr = cmul(cmul(F1, F2), cmul(F3, F4));
        float d = pr.x * pr.x + pr.y * pr.y;
        lg[u] = make_float2(pr.x / d, -pr.y / d);   // 1/prod
    }
    __syncthreads();

    int a   = tid >> 4;   // 0..19 (taps 0..16 valid)
    int sub = tid & 15;
    if (a < A) {
        int ap  = a - K;
        int apu = (ap < 0) ? ap + HP : ap;
        float Pr = 0.f, Pi = 0.f;
        for (int u = sub; u < HP; u += 16) {
            int idx = (u * apu) % HP;
            float2 e = tbl[idx];
            float2 g = lg[u];
            Pr += g.x * e.x - g.y * e.y;
            Pi += g.x * e.y + g.y * e.x;
        }
        red[a][sub] = make_float2(Pr, Pi);
    }
    __syncthreads();
    if (tid < A) {
        float Pr = 0.f, Pi = 0.f;
#pragma unroll
        for (int s2 = 0; s2 < 16; ++s2) { Pr += red[tid][s2].x; Pi += red[tid][s2].y; }
        P[tid * NV + v] = make_float2(Pr, Pi);
    }
}

// g[a,b] = (1/768^2) * sum_v w_v * Re(P[a,v] * exp(+2*pi*i*v*(b-K)/768))
// Stored FLIPPED: gkf[(16-a)*17 + (16-b)] = g[a,b], so deconv reads ascending.
__global__ __launch_bounds__(320) void filt_gk_kernel(
        const float2* __restrict__ P, float* __restrict__ gkf) {
    __shared__ float2 tbl[HP];      // 6144 B
    __shared__ float2 Prow[NV];     // 3080 B
    __shared__ float  red[20][16];  // 1280 B
    int ai  = blockIdx.x;           // 0..16
    int tid = threadIdx.x;

    for (int m = tid; m < HP; m += 320) {
        float s, c;
        sincosf((float)m * TWO_PI_OVER_HP, &s, &c);
        tbl[m] = make_float2(c, s);
    }
    for (int m = tid; m < NV; m += 320)
        Prow[m] = P[ai * NV + m];
    __syncthreads();

    int bi  = tid >> 4;   // 0..19 (taps 0..16 valid)
    int sub = tid & 15;
    if (bi < A) {
        int bp  = bi - K;
        int bpu = (bp < 0) ? bp + HP : bp;
        float sum = 0.f;
        for (int vv = sub; vv < NV; vv += 16) {
            float wv = (vv == 0 || vv == NV - 1) ? 1.f : 2.f;
            int idx = (vv * bpu) % HP;
            float2 e = tbl[idx];
            float2 p = Prow[vv];
            sum += wv * (p.x * e.x - p.y * e.y);
        }
        red[bi][sub] = sum;
    }
    __syncthreads();
    if (tid < A) {
        float s = 0.f;
#pragma unroll
        for (int s2 = 0; s2 < 16; ++s2) s += red[tid][s2];
        gkf[(2 * K - ai) * A + (2 * K - tid)] = s * (1.f / ((float)HP * (float)HP));
    }
}

// Zero everything outside the deconv-covered square [OB, OB+9*64) x [OB, OB+9*64).
__global__ __launch_bounds__(256) void zero_border_kernel(float* __restrict__ out) {
    int gid  = blockIdx.x;            // 64 imgs * 192 row-groups
    int img  = gid / 192;
    int rg   = gid - img * 192;
    int lane = threadIdx.x & 63;
    int w    = threadIdx.x >> 6;      // wave 0..3 -> one row each
    int row  = rg * 4 + w;
    f4v* base = (f4v*)(out + ((size_t)img * HP + row) * HP);
    f4v z = {0.f, 0.f, 0.f, 0.f};
    if (row >= OB && row < OB + NT9 * TH) {
        // side strips: cols [0,120) and [696,768)
        if (lane < ACT0_Q)
            __builtin_nontemporal_store(z, base + lane);
        else if (lane < ACT0_Q + (192 - ACT1_Q))
            __builtin_nontemporal_store(z, base + ACT1_Q + (lane - ACT0_Q));
    } else {
        // full row: 192 float4 = 64 lanes x 3
        __builtin_nontemporal_store(z, base + lane);
        __builtin_nontemporal_store(z, base + lane + 64);
        __builtin_nontemporal_store(z, base + lane + 128);
    }
}

// Direct 17x17 convolution, 9x9 active tiles (origin OB=120).
// TRANSPOSED ROW-FOLD. Exact symmetry: gmf is even in u (u->-u permutes the
// four reference factors; holds despite the rfft-axis truncation) => spatial
// kernel even in y => gkf[r][c] == gkf[16-r][c] EXACTLY (fp noise only).
// [Round-12's column fold was WRONG: the reference reverses the truncated
// 385-col rfft axis, so the b-axis has no such symmetry -> absmax 0.47.]
// Tile staged TRANSPOSED in LDS (compute-rows = input columns); the 8-wide
// register window then runs along y and V_j = r[c+8+j]+r[c+8-j] folds the
// exact axis: 9 FMAs/tap-row instead of 17. Steady per compute-row:
// 64 add + 288 FMA vs 544 FMA (-35% issue). Coefficients gkf[(8+j)*A+(p-m)]
// stay wave-uniform (ty cancels). Outputs re-transposed via LDS once per
// tile before coalesced NT stores.
__global__ __launch_bounds__(128, 3) void deconv_kernel(
        const float* __restrict__ x, const float* __restrict__ gkf,
        float* __restrict__ out) {
    __shared__ __align__(16) float tile[4 * SUBSIZE];   // 26880 B

    const int tx = threadIdx.x;   // 0..7
    const int ty = threadIdx.y;   // 0..15
    const int tid = ty * 8 + tx;
    const int bx = blockIdx.x, by = blockIdx.y, bz = blockIdx.z;

    const int ix0 = bx * TW + (OB - PADO);   // = 64*bx - 16  (% 4 == 0)
    const int iy0 = by * TH + (OB - PADO);
    const int oby = OB + by * TH;            // block's out-row origin
    const int obx = OB + bx * TW;            // block's out-col origin

    // stage input tile TRANSPOSED: tileT[col][row], col-parity layout:
    // word addr = (c&3)*SUBSIZE + (c>>2)*LWS + r. Global reads unchanged
    // (row-major float4, coalesced); each float4 -> 4 ds_write_b32 whose
    // addresses differ by SUBSIZE (distinct banks via c4*LWS spread).
    const float* xb = x + (size_t)bz * (HIN * WIN);
    for (int l = tid; l < LH * (LWL / 4); l += 128) {   // 80*20 = 1600
        int r = l / 20, c4 = l - r * 20;
        int gy = iy0 + r;
        int gx = ix0 + c4 * 4;
        f4v val = {0.f, 0.f, 0.f, 0.f};
        if ((unsigned)gy < (unsigned)HIN && (unsigned)gx < (unsigned)WIN)
            val = *(const f4v*)&xb[gy * WIN + gx];
        float* base = &tile[c4 * LWS + r];
        base[0 * SUBSIZE] = val.x;
        base[1 * SUBSIZE] = val.y;
        base[2 * SUBSIZE] = val.z;
        base[3 * SUBSIZE] = val.w;
    }
    __syncthreads();

    // accT[m][c] = out[oby + tx*8 + c][obx + 4*ty + m]
    float acc0[8], acc1[8], acc2[8], acc3[8];
#pragma unroll
    for (int c = 0; c < 8; ++c) { acc0[c] = 0.f; acc1[c] = 0.f; acc2[c] = 0.f; acc3[c] = 0.f; }

    // bx==8 wave-uniform skip: out cols obx+4ty+m >= OE for ty >= 4; wave 1
    // (ty 8..15) is entirely zero-output -> skip compute, keep accs = 0.
    const bool compute = !(bx == NT9 - 1 && ty >= 8);
    if (compute) {
        // two 24-float windows along y (6 x f4v each)
        f4v rbX[6], rbY[6];
        const float* tlane = tile + ty * LWS + tx * 8;   // per-lane base

        // compute-row q = 4*ty + p (input col rel); q&3 = p&3, q>>2 = ty+(p>>2)
        auto loadRow = [&](f4v* rb, int p) {
            const float* ptr = tlane + (p & 3) * SUBSIZE + (p >> 2) * LWS;
#pragma unroll
            for (int q = 0; q < 6; ++q)
                rb[q] = *(const f4v*)&ptr[q * 4];
        };

#define GETR(r, i) (r[(i) >> 2][(i) & 3])
        // Folded fma: input col p feeds acc m with coefficient col (p-m);
        // fold over the y-taps: V_j = r[c+8+j] + r[c+8-j], coeff gkf[8+j][p-m]
        // (row-even exact). Null acc pointer => tap out of range, elided.
        auto fg = [&](const f4v* r, int pTop,
                      float* A0p, float* A1p, float* A2p, float* A3p) {
#pragma unroll
            for (int j = 0; j <= 8; ++j) {
                float V[8];
#pragma unroll
                for (int c = 0; c < 8; ++c) {
                    V[c] = GETR(r, c + 8 + j);
                    if (j) V[c] += GETR(r, c + 8 - j);
                }
                const float* gj = gkf + (8 + j) * A;
                if (A0p) {
                    float g0 = gj[pTop];
#pragma unroll
                    for (int c = 0; c < 8; ++c) A0p[c] += g0 * V[c];
                }
                if (A1p) {
                    float g1 = gj[pTop - 1];
#pragma unroll
                    for (int c = 0; c < 8; ++c) A1p[c] += g1 * V[c];
                }
                if (A2p) {
                    float g2 = gj[pTop - 2];
#pragma unroll
                    for (int c = 0; c < 8; ++c) A2p[c] += g2 * V[c];
                }
                if (A3p) {
                    float g3 = gj[pTop - 3];
#pragma unroll
                    for (int c = 0; c < 8; ++c) A3p[c] += g3 * V[c];
                }
            }
        };
#undef GETR

        // prologue: p = 0,1,2 (acc_m consumes coeff col p-m when in [0,16])
        loadRow(rbX, 0);
        loadRow(rbY, 1);
        fg(rbX, 0, acc0, nullptr, nullptr, nullptr);
        loadRow(rbX, 2);
        fg(rbY, 1, acc0, acc1, nullptr, nullptr);
        loadRow(rbY, 3);
        fg(rbX, 2, acc0, acc1, acc2, nullptr);

        // steady: p = 3..16, two p per iteration, double-buffered
#pragma unroll 1
        for (int pp = 3; pp <= 15; pp += 2) {
            loadRow(rbX, pp + 1);            // 6 ds_read in flight under fg
            fg(rbY, pp, acc0, acc1, acc2, acc3);
            loadRow(rbY, pp + 2);
            fg(rbX, pp + 1, acc0, acc1, acc2, acc3);
        }

        // epilogue: p = 17,18,19 (rbY holds p=17 from the last iteration)
        fg(rbY, 17, nullptr, acc1, acc2, acc3);
        loadRow(rbX, 18);
        fg(rbX, 18, nullptr, nullptr, acc2, acc3);
        loadRow(rbY, 19);
        fg(rbY, 19, nullptr, nullptr, nullptr, acc3);
    }

    // re-transpose outputs via LDS (reuse tile: 64*65 = 4160 <= 6720 floats)
    __syncthreads();   // all window reads done before overwrite
    float* ot = tile;
#pragma unroll
    for (int c = 0; c < 8; ++c) {
        int r = tx * 8 + c;
        ot[r * OTS + 4 * ty + 0] = acc0[c];
        ot[r * OTS + 4 * ty + 1] = acc1[c];
        ot[r * OTS + 4 * ty + 2] = acc2[c];
        ot[r * OTS + 4 * ty + 3] = acc3[c];
    }
    __syncthreads();

    // coalesced store: 2 threads per out row, 32 cols each (8 x f4v)
    {
        int rr = tid >> 1, half = tid & 1;
        const float* src = &ot[rr * OTS + half * 32];
        float* dst = out + ((size_t)bz * HP + oby + rr) * HP + obx + half * 32;
#pragma unroll
        for (int k = 0; k < 8; ++k) {
            f4v v = *(const f4v*)&src[k * 4];
            __builtin_nontemporal_store(v, (f4v*)&dst[k * 4]);
        }
    }
}

extern "C" void kernel_launch(void* const* d_in, const int* in_sizes, int n_in,
                              void* d_out, int out_size, void* d_ws, size_t ws_size,
                              hipStream_t stream) {
    const float* x = (const float*)d_in[0];   // (64, 512, 512) fp32
    const float* w = (const float*)d_in[1];   // (3, 3) fp32
    float* out = (float*)d_out;               // (64, 768, 768) fp32

    // workspace layout (floats): P = A*NV float2, then gkf = A*A floats
    float2* P   = (float2*)d_ws;
    float*  gkf = (float*)d_ws + (size_t)A * NV * 2;

    filt_P_kernel<<<dim3(NV), dim3(320), 0, stream>>>(w, P);
    filt_gk_kernel<<<dim3(A), dim3(320), 0, stream>>>(P, gkf);
    zero_border_kernel<<<dim3(64 * 192), dim3(256), 0, stream>>>(out);
    deconv_kernel<<<dim3(NT9, NT9, 64), dim3(8, 16), 0, stream>>>(x, gkf, out);
}

// Round 15
// 446.130 us; speedup vs baseline: 6.4722x; 6.4722x over previous
//
#include <hip/hip_runtime.h>

#define HP   768      // padded H (=W)
#define NV   385      // HP/2 + 1
#define HIN  512
#define WIN  512
#define K    8        // truncation radius of spatial inverse kernel
#define A    17       // 2K+1
#define PADO 136      // PAD + K = 128 + 8
#define TW   64       // output tile width
#define TH   64       // output tile height
#define LH   80       // TH + 2K staged rows
#define LWL  80       // TW + 2K (logical tile width)
#define LWS  84       // LDS stride between compute-rows (84 words)
#define SUBROWS 20    // compute-rows per 4-way parity sub-array (80/4)
#define SUBSIZE (SUBROWS * LWS)   // 1680 floats

#define OB   120      // active-region origin: nonzero out rows/cols = [120, 648)
#define OE   648      // active-region end (exclusive)
#define NT9  9        // 9x9 tiles cover [120, 696) >= [120, 648)
#define ACT0_Q 30     // 120/4  (float4 index of active col start)
#define ACT1_Q 174    // 696/4  (float4 index of active col end)
#define OTS  65       // out-transpose LDS row stride (64+1)

#define TWO_PI_OVER_HP 0.008181230868723419f  // 2*pi/768

typedef float f4v __attribute__((ext_vector_type(4)));

__device__ inline float2 cmul(float2 a, float2 b) {
    return make_float2(a.x*b.x - a.y*b.y, a.x*b.y + a.y*b.x);
}

// F(u,v) = sum_{i<3,j<3} w[i,j] * exp(-2*pi*i*(u*i + v*j)/768), via LDS table
__device__ inline float2 evalF_t(int u, int v, const float* w9,
                                 const float2* __restrict__ tbl) {
    float fr = 0.f, fi = 0.f;
#pragma unroll
    for (int i = 0; i < 3; ++i) {
#pragma unroll
        for (int j = 0; j < 3; ++j) {
            int idx = u * i + v * j;          // <= 2302
            if (idx >= 2 * HP) idx -= 2 * HP;
            if (idx >= HP)     idx -= HP;
            float2 e = tbl[idx];
            float wv = w9[i * 3 + j];
            fr += wv * e.x;
            fi -= wv * e.y;
        }
    }
    return make_float2(fr, fi);
}

// One block per rfft column v. Builds gmf[.,v] in LDS, then
// P[a,v] = sum_u gmf[u,v] * exp(+2*pi*i*u*(a-K)/768)  for all 17 taps,
// parallelized 16 threads per tap.
__global__ __launch_bounds__(320) void filt_P_kernel(
        const float* __restrict__ w, float2* __restrict__ P) {
    __shared__ float2 tbl[HP];
    __shared__ float2 lg[HP];
    __shared__ float2 red[20][16];
    int v = blockIdx.x;
    int tid = threadIdx.x;

    float w9[9];
#pragma unroll
    for (int i = 0; i < 9; ++i) w9[i] = w[i];

    for (int m = tid; m < HP; m += 320) {
        float s, c;
        sincosf((float)m * TWO_PI_OVER_HP, &s, &c);
        tbl[m] = make_float2(c, s);
    }
    __syncthreads();

    int sv = (v == 0) ? 0 : (NV - v);   // reference's reverse+roll index
    for (int u = tid; u < HP; u += 320) {
        int su = (HP - u) % HP;
        float2 F1 = evalF_t(u,  v,  w9, tbl);
        float2 F2 = evalF_t(su, v,  w9, tbl);
        float2 F3 = evalF_t(u,  sv, w9, tbl);
        float2 F4 = evalF_t(su, sv, w9, tbl);
        float2 pr = cmul(cmul(F1, F2), cmul(F3, F4));
        float d = pr.x * pr.x + pr.y * pr.y;
        lg[u] = make_float2(pr.x / d, -pr.y / d);   // 1/prod
    }
    __syncthreads();

    int a   = tid >> 4;   // 0..19 (taps 0..16 valid)
    int sub = tid & 15;
    if (a < A) {
        int ap  = a - K;
        int apu = (ap < 0) ? ap + HP : ap;
        float Pr = 0.f, Pi = 0.f;
        for (int u = sub; u < HP; u += 16) {
            int idx = (u * apu) % HP;
            float2 e = tbl[idx];
            float2 g = lg[u];
            Pr += g.x * e.x - g.y * e.y;
            Pi += g.x * e.y + g.y * e.x;
        }
        red[a][sub] = make_float2(Pr, Pi);
    }
    __syncthreads();
    if (tid < A) {
        float Pr = 0.f, Pi = 0.f;
#pragma unroll
        for (int s2 = 0; s2 < 16; ++s2) { Pr += red[tid][s2].x; Pi += red[tid][s2].y; }
        P[tid * NV + v] = make_float2(Pr, Pi);
    }
}

// g[a,b] = (1/768^2) * sum_v w_v * Re(P[a,v] * exp(+2*pi*i*v*(b-K)/768))
// Stored FLIPPED: gkf[(16-a)*17 + (16-b)] = g[a,b], so deconv reads ascending.
__global__ __launch_bounds__(320) void filt_gk_kernel(
        const float2* __restrict__ P, float* __restrict__ gkf) {
    __shared__ float2 tbl[HP];      // 6144 B
    __shared__ float2 Prow[NV];     // 3080 B
    __shared__ float  red[20][16];  // 1280 B
    int ai  = blockIdx.x;           // 0..16
    int tid = threadIdx.x;

    for (int m = tid; m < HP; m += 320) {
        float s, c;
        sincosf((float)m * TWO_PI_OVER_HP, &s, &c);
        tbl[m] = make_float2(c, s);
    }
    for (int m = tid; m < NV; m += 320)
        Prow[m] = P[ai * NV + m];
    __syncthreads();

    int bi  = tid >> 4;   // 0..19 (taps 0..16 valid)
    int sub = tid & 15;
    if (bi < A) {
        int bp  = bi - K;
        int bpu = (bp < 0) ? bp + HP : bp;
        float sum = 0.f;
        for (int vv = sub; vv < NV; vv += 16) {
            float wv = (vv == 0 || vv == NV - 1) ? 1.f : 2.f;
            int idx = (vv * bpu) % HP;
            float2 e = tbl[idx];
            float2 p = Prow[vv];
            sum += wv * (p.x * e.x - p.y * e.y);
        }
        red[bi][sub] = sum;
    }
    __syncthreads();
    if (tid < A) {
        float s = 0.f;
#pragma unroll
        for (int s2 = 0; s2 < 16; ++s2) s += red[tid][s2];
        gkf[(2 * K - ai) * A + (2 * K - tid)] = s * (1.f / ((float)HP * (float)HP));
    }
}

// Zero everything outside the deconv-covered square [OB, OB+9*64) x [OB, OB+9*64).
__global__ __launch_bounds__(256) void zero_border_kernel(float* __restrict__ out) {
    int gid  = blockIdx.x;            // 64 imgs * 192 row-groups
    int img  = gid / 192;
    int rg   = gid - img * 192;
    int lane = threadIdx.x & 63;
    int w    = threadIdx.x >> 6;      // wave 0..3 -> one row each
    int row  = rg * 4 + w;
    f4v* base = (f4v*)(out + ((size_t)img * HP + row) * HP);
    f4v z = {0.f, 0.f, 0.f, 0.f};
    if (row >= OB && row < OB + NT9 * TH) {
        // side strips: cols [0,120) and [696,768)
        if (lane < ACT0_Q)
            __builtin_nontemporal_store(z, base + lane);
        else if (lane < ACT0_Q + (192 - ACT1_Q))
            __builtin_nontemporal_store(z, base + ACT1_Q + (lane - ACT0_Q));
    } else {
        // full row: 192 float4 = 64 lanes x 3
        __builtin_nontemporal_store(z, base + lane);
        __builtin_nontemporal_store(z, base + lane + 64);
        __builtin_nontemporal_store(z, base + lane + 128);
    }
}

// Direct 17x17 convolution, 9x9 active tiles (origin OB=120).
// TRANSPOSED ROW-FOLD (math verified on HW: absmax 0.03125, round 14).
// gmf is even in u => gkf[r][c] == gkf[16-r][c]; tile staged transposed so
// the 8-wide register window runs along y; V_j = r[c+8+j]+r[c+8-j] folds the
// exact axis (9 FMAs/tap-row instead of 17; -35% issue).
// ROUND-15 FIX: round 14 passed accumulators as runtime POINTER args with
// nullptr guards into the fold lambda -> address escape -> SROA defeated ->
// accs in SCRATCH (WRITE_SIZE 4 GB, VALUBusy 2%, 2811us). The fold is now a
// MACRO with compile-time 0/1 enables; acc0..acc3 referenced by name with
// static indices only -> guaranteed VGPR residency (rule #20).
__global__ __launch_bounds__(128, 3) void deconv_kernel(
        const float* __restrict__ x, const float* __restrict__ gkf,
        float* __restrict__ out) {
    __shared__ __align__(16) float tile[4 * SUBSIZE];   // 26880 B

    const int tx = threadIdx.x;   // 0..7
    const int ty = threadIdx.y;   // 0..15
    const int tid = ty * 8 + tx;
    const int bx = blockIdx.x, by = blockIdx.y, bz = blockIdx.z;

    const int ix0 = bx * TW + (OB - PADO);   // = 64*bx - 16  (% 4 == 0)
    const int iy0 = by * TH + (OB - PADO);
    const int oby = OB + by * TH;            // block's out-row origin
    const int obx = OB + bx * TW;            // block's out-col origin

    // stage input tile TRANSPOSED: tileT[col][row], col-parity layout:
    // word addr = (c&3)*SUBSIZE + (c>>2)*LWS + r. Global reads unchanged
    // (row-major float4, coalesced); each float4 -> 4 ds_write_b32.
    const float* xb = x + (size_t)bz * (HIN * WIN);
    for (int l = tid; l < LH * (LWL / 4); l += 128) {   // 80*20 = 1600
        int r = l / 20, c4 = l - r * 20;
        int gy = iy0 + r;
        int gx = ix0 + c4 * 4;
        f4v val = {0.f, 0.f, 0.f, 0.f};
        if ((unsigned)gy < (unsigned)HIN && (unsigned)gx < (unsigned)WIN)
            val = *(const f4v*)&xb[gy * WIN + gx];
        float* base = &tile[c4 * LWS + r];
        base[0 * SUBSIZE] = val.x;
        base[1 * SUBSIZE] = val.y;
        base[2 * SUBSIZE] = val.z;
        base[3 * SUBSIZE] = val.w;
    }
    __syncthreads();

    // accT[m][c] = out[oby + tx*8 + c][obx + 4*ty + m]
    float acc0[8], acc1[8], acc2[8], acc3[8];
#pragma unroll
    for (int c = 0; c < 8; ++c) { acc0[c] = 0.f; acc1[c] = 0.f; acc2[c] = 0.f; acc3[c] = 0.f; }

    // bx==8 wave-uniform skip: out cols obx+4ty+m >= OE for ty >= 4; wave 1
    // (ty 8..15) is entirely zero-output -> skip compute, keep accs = 0.
    const bool compute = !(bx == NT9 - 1 && ty >= 8);
    if (compute) {
        // two 24-float windows along y (6 x f4v each)
        f4v rbX[6], rbY[6];
        const float* tlane = tile + ty * LWS + tx * 8;   // per-lane base

        // compute-row q = 4*ty + p (input col rel); q&3 = p&3, q>>2 = ty+(p>>2)
        auto loadRow = [&](f4v* rb, int p) {
            const float* ptr = tlane + (p & 3) * SUBSIZE + (p >> 2) * LWS;
#pragma unroll
            for (int q = 0; q < 6; ++q)
                rb[q] = *(const f4v*)&ptr[q * 4];
        };

#define GETR(rw, i) (rw[(i) >> 2][(i) & 3])
        // Folded fma, scratch-proof: enables are LITERAL 0/1; accumulators
        // named directly (no pointers, no escape). Input col pTop feeds
        // acc m with coefficient col (pTop - m); V_j folds the y-taps.
#define FG(rw, pTop, E0, E1, E2, E3)                                       \
        do {                                                               \
            _Pragma("unroll")                                              \
            for (int j = 0; j <= 8; ++j) {                                 \
                float V[8];                                                \
                _Pragma("unroll")                                          \
                for (int c = 0; c < 8; ++c) {                              \
                    V[c] = GETR(rw, c + 8 + j);                            \
                    if (j) V[c] += GETR(rw, c + 8 - j);                    \
                }                                                          \
                const float* gj = gkf + (8 + j) * A;                       \
                if (E0) { float g0 = gj[(pTop)];                           \
                    _Pragma("unroll")                                      \
                    for (int c = 0; c < 8; ++c) acc0[c] += g0 * V[c]; }    \
                if (E1) { float g1 = gj[(pTop) - 1];                       \
                    _Pragma("unroll")                                      \
                    for (int c = 0; c < 8; ++c) acc1[c] += g1 * V[c]; }    \
                if (E2) { float g2 = gj[(pTop) - 2];                       \
                    _Pragma("unroll")                                      \
                    for (int c = 0; c < 8; ++c) acc2[c] += g2 * V[c]; }    \
                if (E3) { float g3 = gj[(pTop) - 3];                       \
                    _Pragma("unroll")                                      \
                    for (int c = 0; c < 8; ++c) acc3[c] += g3 * V[c]; }    \
            }                                                              \
        } while (0)

        // prologue: p = 0,1,2 (acc_m consumes coeff col p-m when in [0,16])
        loadRow(rbX, 0);
        loadRow(rbY, 1);
        FG(rbX, 0, 1, 0, 0, 0);
        loadRow(rbX, 2);
        FG(rbY, 1, 1, 1, 0, 0);
        loadRow(rbY, 3);
        FG(rbX, 2, 1, 1, 1, 0);

        // steady: p = 3..16, two p per iteration, double-buffered
#pragma unroll 1
        for (int pp = 3; pp <= 15; pp += 2) {
            loadRow(rbX, pp + 1);            // 6 ds_read in flight under FG
            FG(rbY, pp, 1, 1, 1, 1);
            loadRow(rbY, pp + 2);
            FG(rbX, pp + 1, 1, 1, 1, 1);
        }

        // epilogue: p = 17,18,19 (rbY holds p=17 from the last iteration)
        FG(rbY, 17, 0, 1, 1, 1);
        loadRow(rbX, 18);
        FG(rbX, 18, 0, 0, 1, 1);
        loadRow(rbY, 19);
        FG(rbY, 19, 0, 0, 0, 1);
#undef FG
#undef GETR
    }

    // re-transpose outputs via LDS (reuse tile: 64*65 = 4160 <= 6720 floats)
    __syncthreads();   // all window reads done before overwrite
    float* ot = tile;
#pragma unroll
    for (int c = 0; c < 8; ++c) {
        int r = tx * 8 + c;
        ot[r * OTS + 4 * ty + 0] = acc0[c];
        ot[r * OTS + 4 * ty + 1] = acc1[c];
        ot[r * OTS + 4 * ty + 2] = acc2[c];
        ot[r * OTS + 4 * ty + 3] = acc3[c];
    }
    __syncthreads();

    // coalesced store: 2 threads per out row, 32 cols each (8 x f4v)
    {
        int rr = tid >> 1, half = tid & 1;
        const float* src = &ot[rr * OTS + half * 32];
        float* dst = out + ((size_t)bz * HP + oby + rr) * HP + obx + half * 32;
#pragma unroll
        for (int k = 0; k < 8; ++k) {
            f4v v = *(const f4v*)&src[k * 4];
            __builtin_nontemporal_store(v, (f4v*)&dst[k * 4]);
        }
    }
}

extern "C" void kernel_launch(void* const* d_in, const int* in_sizes, int n_in,
                              void* d_out, int out_size, void* d_ws, size_t ws_size,
                              hipStream_t stream) {
    const float* x = (const float*)d_in[0];   // (64, 512, 512) fp32
    const float* w = (const float*)d_in[1];   // (3, 3) fp32
    float* out = (float*)d_out;               // (64, 768, 768) fp32

    // workspace layout (floats): P = A*NV float2, then gkf = A*A floats
    float2* P   = (float2*)d_ws;
    float*  gkf = (float*)d_ws + (size_t)A * NV * 2;

    filt_P_kernel<<<dim3(NV), dim3(320), 0, stream>>>(w, P);
    filt_gk_kernel<<<dim3(A), dim3(320), 0, stream>>>(P, gkf);
    zero_border_kernel<<<dim3(64 * 192), dim3(256), 0, stream>>>(out);
    deconv_kernel<<<dim3(NT9, NT9, 64), dim3(8, 16), 0, stream>>>(x, gkf, out);
}